// Round 12
// baseline (182.220 us; speedup 1.0000x reference)
//
#include <hip/hip_runtime.h>
#include <hip/hip_bf16.h>
#include <stdint.h>

#define B_ 8
#define L_ 2048
#define D_ 1024
#define N_ 16
#define M_ (B_ * L_)   // 16384 rows
#define K_ D_          // 1024
#define SEG_ 64
#define SLEN_ (L_ / SEG_)   // 32
#define LOG2E 1.44269504088896341f

typedef __bf16 bf16;
typedef __bf16 bf16x8 __attribute__((ext_vector_type(8)));
typedef float f32x4 __attribute__((ext_vector_type(4)));

// ---------------- f32 -> bf16 conversion (vectorized x4) ----------------
__global__ __launch_bounds__(256) void cvt_f32_bf16(const float* __restrict__ in,
                                                    bf16* __restrict__ out, int n4) {
  int i = blockIdx.x * 256 + threadIdx.x;
  const int stride = gridDim.x * 256;
  const float4* in4 = (const float4*)in;
  uint2* out2 = (uint2*)out;
  for (; i < n4; i += stride) {
    float4 v = in4[i];
    union { bf16 h[4]; uint2 u; } p;
    p.h[0] = (bf16)v.x; p.h[1] = (bf16)v.y; p.h[2] = (bf16)v.z; p.h[3] = (bf16)v.w;
    out2[i] = p.u;
  }
}

// ---------------- async global->LDS helper (16B) ----------------
__device__ inline void gload_lds16(const bf16* g, bf16* l) {
  __builtin_amdgcn_global_load_lds(
      (const __attribute__((address_space(1))) void*)g,
      (__attribute__((address_space(3))) void*)l, 16, 0, 0);
}

__device__ inline float softplus_f(float z) {
  return fmaxf(z, 0.f) + __logf(1.f + __expf(-fabsf(z)));
}

// ---------------- dt GEMM: dtb = bf16(softplus(Xb @ Wdb^T + bd)) ----------------
// R8-proven 2-phase: 128x128 tile, BK=32, 4 waves, double-buffered, both-sides
// LDS XOR-swizzle, XCD-chunked block swizzle. 54.5 us / 630 TF (2-phase ceiling).
__global__ __launch_bounds__(256) void gemm_dt(const bf16* __restrict__ Xb,
                                               const bf16* __restrict__ Wdb,
                                               const float* __restrict__ bd,
                                               bf16* __restrict__ dtb) {
  __shared__ bf16 As[2][128 * 32];
  __shared__ bf16 Bs[2][128 * 32];
  const int tid = threadIdx.x;
  const int lane = tid & 63;
  const int wave = tid >> 6;
  const int wr = wave >> 1, wc = wave & 1;
  const int virt = (blockIdx.x & 7) * 128 + (blockIdx.x >> 3);
  const int mt = virt >> 3, nt = virt & 7;
  const int m0 = mt * 128, n0 = nt * 128;

  const bf16* ga[2];
  const bf16* gb[2];
#pragma unroll
  for (int q = 0; q < 2; ++q) {
    const int c = tid + 256 * q;
    const int row = c >> 2;
    const int col8 = ((c & 3) ^ (row & 3)) * 8;
    ga[q] = Xb + (size_t)(m0 + row) * K_ + col8;
    gb[q] = Wdb + (size_t)(n0 + row) * K_ + col8;
  }

  f32x4 acc[4][4] = {};
  const int frow = (lane & 15);
  const int khalf = (lane >> 4);   // 0..3

  int aoff[4], boff[4];
#pragma unroll
  for (int i = 0; i < 4; ++i) {
    const int Ra = wr * 64 + i * 16 + frow;
    const int Rb = wc * 64 + i * 16 + frow;
    aoff[i] = Ra * 32 + (khalf ^ (Ra & 3)) * 8;
    boff[i] = Rb * 32 + (khalf ^ (Rb & 3)) * 8;
  }

#define STAGE_(buf, kt)                                         \
  {                                                             \
    gload_lds16(ga[0] + (kt), &As[buf][tid * 8]);               \
    gload_lds16(ga[1] + (kt), &As[buf][(tid + 256) * 8]);       \
    gload_lds16(gb[0] + (kt), &Bs[buf][tid * 8]);               \
    gload_lds16(gb[1] + (kt), &Bs[buf][(tid + 256) * 8]);       \
  }

  STAGE_(0, 0);
  __syncthreads();

  int cur = 0;
  for (int t = 0; t < K_ / 32; ++t) {
    if (t + 1 < K_ / 32) STAGE_(cur ^ 1, (t + 1) * 32);
    bf16x8 af[4], bfr[4];
#pragma unroll
    for (int i = 0; i < 4; ++i) af[i] = *(const bf16x8*)&As[cur][aoff[i]];
#pragma unroll
    for (int i = 0; i < 4; ++i) bfr[i] = *(const bf16x8*)&Bs[cur][boff[i]];
#pragma unroll
    for (int i = 0; i < 4; ++i)
#pragma unroll
      for (int j = 0; j < 4; ++j)
        acc[i][j] = __builtin_amdgcn_mfma_f32_16x16x32_bf16(af[i], bfr[j], acc[i][j], 0, 0, 0);
    __syncthreads();
    cur ^= 1;
  }
#undef STAGE_

  const int rbase = m0 + wr * 64 + (lane >> 4) * 4;
  const int cbase = n0 + wc * 64 + (lane & 15);
#pragma unroll
  for (int j = 0; j < 4; ++j) {
    const int col = cbase + j * 16;
    const float bias = bd[col];
#pragma unroll
    for (int i = 0; i < 4; ++i) {
      const int row = rbase + i * 16;
#pragma unroll
      for (int r = 0; r < 4; ++r) {
        float z = acc[i][j][r] + bias;
        dtb[(size_t)(row + r) * D_ + col] = (bf16)softplus_f(z);
      }
    }
  }
}

// ---------------- Bx = x @ Wb^T via MFMA ([M_,16]) ----------------
__global__ __launch_bounds__(256) void bx_mfma(const bf16* __restrict__ Xb,
                                               const bf16* __restrict__ Wbb,
                                               float* __restrict__ Bx) {
  const int lane = threadIdx.x & 63;
  const int wave = threadIdx.x >> 6;
  const int row0 = blockIdx.x * 64 + wave * 16;
  const int fr = lane & 15;
  const int kg = (lane >> 4) * 8;
  const bf16* ga = Xb + (size_t)(row0 + fr) * K_ + kg;
  const bf16* gb = Wbb + (size_t)fr * K_ + kg;
  f32x4 acc = {};
#pragma unroll 8
  for (int kt = 0; kt < K_; kt += 32) {
    bf16x8 af = *(const bf16x8*)(ga + kt);
    bf16x8 bf = *(const bf16x8*)(gb + kt);
    acc = __builtin_amdgcn_mfma_f32_16x16x32_bf16(af, bf, acc, 0, 0, 0);
  }
  const int orow = row0 + (lane >> 4) * 4;
  const int ocol = lane & 15;
#pragma unroll
  for (int r = 0; r < 4; ++r)
    Bx[(size_t)(orow + r) * N_ + ocol] = acc[r];
}

// ---------------- pass 1: per-segment summaries, n-split across lane halves ----
// thread = (b, d, seg, half); half owns 8 n-states. grid = B_*8*SEG_ = 4096.
// Within a wave: d = dtile*128 + wave*32 + (lane&31), half = lane>>5.
__global__ __launch_bounds__(256) void scan_p1(
    const bf16* __restrict__ dtb, const float* __restrict__ Bx,
    const float* __restrict__ A, bf16* __restrict__ hseg,
    float* __restrict__ stot) {
  const int tid = threadIdx.x;
  const int bi = blockIdx.x;
  const int seg = bi & 63;
  const int dtile = (bi >> 6) & 7;
  const int b = bi >> 9;
  const int lane = tid & 63;
  const int wave = tid >> 6;
  const int half = lane >> 5;
  const int d = dtile * 128 + wave * 32 + (lane & 31);
  const int l0 = seg * SLEN_;

  const float* bxp = Bx + ((size_t)b * L_ + l0) * N_ + half * 8;  // half-uniform

  float A2[8];
  {
    const float4* ap = (const float4*)(A + (size_t)d * N_ + half * 8);
#pragma unroll
    for (int q = 0; q < 2; ++q) {
      float4 a = ap[q];
      A2[q * 4 + 0] = a.x * LOG2E; A2[q * 4 + 1] = a.y * LOG2E;
      A2[q * 4 + 2] = a.z * LOG2E; A2[q * 4 + 3] = a.w * LOG2E;
    }
  }

  const bf16* dtp = dtb + ((size_t)b * L_ + l0) * D_ + d;
  float h[8] = {};
  float s = 0.f;

  float cdt[2];
#pragma unroll
  for (int u = 0; u < 2; ++u) cdt[u] = (float)dtp[(size_t)u * D_];

#define P1_STEP(i, c0)                                              \
  {                                                                 \
    s += (c0);                                                      \
    _Pragma("unroll")                                               \
    for (int q = 0; q < 2; ++q) {                                   \
      const float4 bv = *(const float4*)(bxp + (i) * N_ + q * 4);   \
      const float bvf[4] = {bv.x, bv.y, bv.z, bv.w};                \
      _Pragma("unroll")                                             \
      for (int j = 0; j < 4; ++j) {                                 \
        const int n = q * 4 + j;                                    \
        const float e = __builtin_amdgcn_exp2f((c0) * A2[n]);       \
        h[n] = fmaf(e, h[n], (c0) * bvf[j]);                        \
      }                                                             \
    }                                                               \
  }

  for (int i0 = 0; i0 < SLEN_ - 2; i0 += 2) {
#pragma unroll
    for (int u = 0; u < 2; ++u) {
      const int i = i0 + u;
      const float c0 = cdt[u];
      cdt[u] = (float)dtp[(size_t)(i + 2) * D_];
      P1_STEP(i, c0);
    }
  }
#pragma unroll
  for (int u = 0; u < 2; ++u) {
    const int i = SLEN_ - 2 + u;
    P1_STEP(i, cdt[u]);
  }
#undef P1_STEP

  bf16* hp = hseg + (((size_t)b * SEG_ + seg) * D_ + d) * N_ + half * 8;
  union { bf16 v[8]; uint4 u; } pk;
#pragma unroll
  for (int n = 0; n < 8; ++n) pk.v[n] = (bf16)h[n];
  *(uint4*)hp = pk.u;
  if (half == 0) stot[((size_t)b * SEG_ + seg) * D_ + d] = s;
}

// ---------------- pass 2: exclusive-prefix combine (in-place hseg -> h0) ----
__global__ __launch_bounds__(256) void scan_combine(
    const float* __restrict__ A, bf16* __restrict__ hseg,
    const float* __restrict__ stot) {
  const int tid = threadIdx.x;
  const int bi = blockIdx.x;          // B_ * (D_/16) = 512
  const int b = bi >> 6;
  const int d = (bi & 63) * 16 + (tid >> 4);
  const int n = tid & 15;
  const float A2 = A[(size_t)d * N_ + n] * LOG2E;

  const size_t hbase = ((size_t)b * SEG_ * D_ + d) * N_ + n;
  const size_t sbase = (size_t)b * SEG_ * D_ + d;
  float g = 0.f;
  float hs = (float)hseg[hbase];
  float st = stot[sbase];
  for (int sg = 0; sg < SEG_; ++sg) {
    const int s1 = (sg + 1 < SEG_) ? sg + 1 : sg;
    const float nhs = (float)hseg[hbase + (size_t)s1 * D_ * N_];
    const float nst = stot[sbase + (size_t)s1 * D_];
    hseg[hbase + (size_t)sg * D_ * N_] = (bf16)g;
    g = fmaf(__builtin_amdgcn_exp2f(A2 * st), g, hs);
    hs = nhs; st = nst;
  }
}

// ---------------- pass 3: full recurrence from h0, n-split across lane halves --
// y combined via __shfl_xor(.,32); Dp*x added in half 0 only; half 0 stores.
__global__ __launch_bounds__(256) void scan_p3(
    const bf16* __restrict__ dtb, const float* __restrict__ Bx,
    const bf16* __restrict__ xb, const float* __restrict__ A,
    const float* __restrict__ C, const float* __restrict__ Dp,
    const bf16* __restrict__ hseg, float* __restrict__ out) {
  const int tid = threadIdx.x;
  const int bi = blockIdx.x;
  const int seg = bi & 63;
  const int dtile = (bi >> 6) & 7;
  const int b = bi >> 9;
  const int lane = tid & 63;
  const int wave = tid >> 6;
  const int half = lane >> 5;
  const int d = dtile * 128 + wave * 32 + (lane & 31);
  const int l0 = seg * SLEN_;

  const float* bxp = Bx + ((size_t)b * L_ + l0) * N_ + half * 8;

  float A2[8], Cv[8], h[8];
  {
    const float4* ap = (const float4*)(A + (size_t)d * N_ + half * 8);
    const float4* cp = (const float4*)(C + (size_t)d * N_ + half * 8);
    const bf16* hp = hseg + (((size_t)b * SEG_ + seg) * D_ + d) * N_ + half * 8;
    union { uint4 u; bf16 v[8]; } pk;
    pk.u = *(const uint4*)hp;
#pragma unroll
    for (int q = 0; q < 2; ++q) {
      float4 a = ap[q], c = cp[q];
      A2[q * 4 + 0] = a.x * LOG2E; A2[q * 4 + 1] = a.y * LOG2E;
      A2[q * 4 + 2] = a.z * LOG2E; A2[q * 4 + 3] = a.w * LOG2E;
      Cv[q * 4 + 0] = c.x; Cv[q * 4 + 1] = c.y;
      Cv[q * 4 + 2] = c.z; Cv[q * 4 + 3] = c.w;
    }
#pragma unroll
    for (int n = 0; n < 8; ++n) h[n] = (float)pk.v[n];
  }
  const float Dpv = (half == 0) ? Dp[d] : 0.f;

  const size_t base = ((size_t)b * L_ + l0) * D_ + d;
  const bf16* dtp = dtb + base;
  const bf16* xp = xb + base;
  float* op = out + base;

  float cdt[2], cx[2];
#pragma unroll
  for (int u = 0; u < 2; ++u) {
    cdt[u] = (float)dtp[(size_t)u * D_];
    cx[u]  = (float)xp[(size_t)u * D_];
  }

#define P3_STEP(i, c0, x0)                                          \
  {                                                                 \
    float y = Dpv * (x0);                                           \
    _Pragma("unroll")                                               \
    for (int q = 0; q < 2; ++q) {                                   \
      const float4 bv = *(const float4*)(bxp + (i) * N_ + q * 4);   \
      const float bvf[4] = {bv.x, bv.y, bv.z, bv.w};                \
      _Pragma("unroll")                                             \
      for (int j = 0; j < 4; ++j) {                                 \
        const int n = q * 4 + j;                                    \
        const float e = __builtin_amdgcn_exp2f((c0) * A2[n]);       \
        h[n] = fmaf(e, h[n], (c0) * bvf[j]);                        \
        y = fmaf(h[n], Cv[n], y);                                   \
      }                                                             \
    }                                                               \
    y += __shfl_xor(y, 32);                                         \
    if (half == 0) op[(size_t)(i) * D_] = y;                        \
  }

  for (int i0 = 0; i0 < SLEN_ - 2; i0 += 2) {
#pragma unroll
    for (int u = 0; u < 2; ++u) {
      const int i = i0 + u;
      const float c0 = cdt[u], x0 = cx[u];
      cdt[u] = (float)dtp[(size_t)(i + 2) * D_];
      cx[u]  = (float)xp[(size_t)(i + 2) * D_];
      P3_STEP(i, c0, x0);
    }
  }
#pragma unroll
  for (int u = 0; u < 2; ++u) {
    const int i = SLEN_ - 2 + u;
    P3_STEP(i, cdt[u], cx[u]);
  }
#undef P3_STEP
}

// ---------------- launch ----------------
extern "C" void kernel_launch(void* const* d_in, const int* in_sizes, int n_in,
                              void* d_out, int out_size, void* d_ws, size_t ws_size,
                              hipStream_t stream) {
  const float* x  = (const float*)d_in[0];
  const float* A  = (const float*)d_in[1];
  const float* Wb = (const float*)d_in[2];
  const float* C  = (const float*)d_in[3];
  const float* Dp = (const float*)d_in[4];
  const float* Wd = (const float*)d_in[5];
  const float* bd = (const float*)d_in[6];
  float* out = (float*)d_out;

  char* ws = (char*)d_ws;
  bf16*  dtb  = (bf16*)ws;                                  // 32 MB [M,D] bf16
  bf16*  xb   = (bf16*)(ws + (size_t)33554432);             // 32 MB [M,K] bf16
  bf16*  wdb  = (bf16*)(ws + (size_t)67108864);             //  2 MB [D,K] bf16
  bf16*  wbb  = (bf16*)(ws + (size_t)69206016);             // 32 KB [16,K] bf16
  float* bx   = (float*)(ws + (size_t)69238784);            //  1 MB [M,16] f32
  bf16*  hseg = (bf16*)(ws + (size_t)70287360);             // 16 MB [B][SEG][D][N] bf16
  float* stot = (float*)(ws + (size_t)87064576);            //  2 MB [B][SEG][D] f32

  cvt_f32_bf16<<<2048, 256, 0, stream>>>(x, xb, M_ * K_ / 4);
  cvt_f32_bf16<<<1024, 256, 0, stream>>>(Wd, wdb, D_ * K_ / 4);
  cvt_f32_bf16<<<16, 256, 0, stream>>>(Wb, wbb, N_ * K_ / 4);
  bx_mfma<<<dim3(M_ / 64), 256, 0, stream>>>(xb, wbb, bx);
  gemm_dt<<<dim3((M_ / 128) * (D_ / 128)), 256, 0, stream>>>(xb, wdb, bd, dtb);
  scan_p1<<<dim3(B_ * 8 * SEG_), 256, 0, stream>>>(dtb, bx, A, hseg, stot);
  scan_combine<<<dim3(B_ * (D_ / 16)), 256, 0, stream>>>(A, hseg, stot);
  scan_p3<<<dim3(B_ * 8 * SEG_), 256, 0, stream>>>(dtb, bx, xb, A, C, Dp, hseg, out);
}

// Round 13
// 165.337 us; speedup vs baseline: 1.1021x; 1.1021x over previous
//
#include <hip/hip_runtime.h>
#include <hip/hip_bf16.h>
#include <stdint.h>

#define B_ 8
#define L_ 2048
#define D_ 1024
#define N_ 16
#define M_ (B_ * L_)   // 16384 rows
#define K_ D_          // 1024
#define SEG_ 64
#define SLEN_ (L_ / SEG_)   // 32
#define LOG2E 1.44269504088896341f

typedef __bf16 bf16;
typedef __bf16 bf16x8 __attribute__((ext_vector_type(8)));
typedef float f32x4 __attribute__((ext_vector_type(4)));
typedef float f32x2 __attribute__((ext_vector_type(2)));

// ---------------- Wd + Wb f32->bf16 conversion (single launch) ----------------
__global__ __launch_bounds__(256) void cvt_wdwb(const float* __restrict__ Wd,
                                                const float* __restrict__ Wb,
                                                bf16* __restrict__ wdb,
                                                bf16* __restrict__ wbb) {
  const int bi = blockIdx.x;
  const float4* in4;
  uint2* out2;
  int i;
  if (bi < 1024) {            // Wd: 1M elems = 262144 float4
    i = bi * 256 + threadIdx.x;
    in4 = (const float4*)Wd;
    out2 = (uint2*)wdb;
  } else {                    // Wb: 16384 elems = 4096 float4 (16 blocks)
    i = (bi - 1024) * 256 + threadIdx.x;
    in4 = (const float4*)Wb;
    out2 = (uint2*)wbb;
  }
  float4 v = in4[i];
  union { bf16 h[4]; uint2 u; } p;
  p.h[0] = (bf16)v.x; p.h[1] = (bf16)v.y; p.h[2] = (bf16)v.z; p.h[3] = (bf16)v.w;
  out2[i] = p.u;
}

// ---------------- prep_x: x->bf16 (writes xb) fused with Bx = x @ Wb^T -------
// 1024 blocks x 256 thr. Block = 16 rows; wave w handles K-quarter w*256..+256.
// Converted frags feed MFMA directly from registers; 4 partial accs LDS-reduced.
__global__ __launch_bounds__(256) void prep_x(const float* __restrict__ x,
                                              const bf16* __restrict__ Wbb,
                                              bf16* __restrict__ xb,
                                              float* __restrict__ Bx) {
  const int lane = threadIdx.x & 63;
  const int wave = threadIdx.x >> 6;
  const int row0 = blockIdx.x * 16;
  const int fr = lane & 15;
  const int kg = (lane >> 4) * 8;
  const int k0 = wave * 256;
  const float* gx = x + (size_t)(row0 + fr) * K_ + k0 + kg;
  const bf16* gb = Wbb + (size_t)fr * K_ + k0 + kg;
  bf16* gxb = xb + (size_t)(row0 + fr) * K_ + k0 + kg;

  f32x4 acc = {};
#pragma unroll 8
  for (int kt = 0; kt < 8; ++kt) {
    float4 v0 = *(const float4*)(gx + kt * 32);
    float4 v1 = *(const float4*)(gx + kt * 32 + 4);
    union { bf16 h[8]; bf16x8 v; uint4 u; } p;
    p.h[0] = (bf16)v0.x; p.h[1] = (bf16)v0.y; p.h[2] = (bf16)v0.z; p.h[3] = (bf16)v0.w;
    p.h[4] = (bf16)v1.x; p.h[5] = (bf16)v1.y; p.h[6] = (bf16)v1.z; p.h[7] = (bf16)v1.w;
    *(uint4*)(gxb + kt * 32) = p.u;
    bf16x8 bf = *(const bf16x8*)(gb + kt * 32);
    acc = __builtin_amdgcn_mfma_f32_16x16x32_bf16(p.v, bf, acc, 0, 0, 0);
  }

  __shared__ float red[4][16][17];   // +1 pad breaks ds bank conflicts
  const int orow = (lane >> 4) * 4, ocol = fr;
#pragma unroll
  for (int r = 0; r < 4; ++r) red[wave][orow + r][ocol] = acc[r];
  __syncthreads();
  const int rr = threadIdx.x >> 4, cc = threadIdx.x & 15;
  const float s = red[0][rr][cc] + red[1][rr][cc] + red[2][rr][cc] + red[3][rr][cc];
  Bx[(size_t)(row0 + rr) * N_ + cc] = s;
}

// ---------------- async global->LDS helper (16B) ----------------
__device__ inline void gload_lds16(const bf16* g, bf16* l) {
  __builtin_amdgcn_global_load_lds(
      (const __attribute__((address_space(1))) void*)g,
      (__attribute__((address_space(3))) void*)l, 16, 0, 0);
}

__device__ inline float softplus_f(float z) {
  return fmaxf(z, 0.f) + __logf(1.f + __expf(-fabsf(z)));
}

// ---------------- dt GEMM: dtb = bf16(softplus(Xb @ Wdb^T + bd)) ----------------
// R8-proven 2-phase: 128x128 tile, BK=32, 4 waves, double-buffered, both-sides
// LDS XOR-swizzle, XCD-chunked block swizzle. 54.5 us / 630 TF (2-phase ceiling).
__global__ __launch_bounds__(256) void gemm_dt(const bf16* __restrict__ Xb,
                                               const bf16* __restrict__ Wdb,
                                               const float* __restrict__ bd,
                                               bf16* __restrict__ dtb) {
  __shared__ bf16 As[2][128 * 32];
  __shared__ bf16 Bs[2][128 * 32];
  const int tid = threadIdx.x;
  const int lane = tid & 63;
  const int wave = tid >> 6;
  const int wr = wave >> 1, wc = wave & 1;
  const int virt = (blockIdx.x & 7) * 128 + (blockIdx.x >> 3);
  const int mt = virt >> 3, nt = virt & 7;
  const int m0 = mt * 128, n0 = nt * 128;

  const bf16* ga[2];
  const bf16* gb[2];
#pragma unroll
  for (int q = 0; q < 2; ++q) {
    const int c = tid + 256 * q;
    const int row = c >> 2;
    const int col8 = ((c & 3) ^ (row & 3)) * 8;
    ga[q] = Xb + (size_t)(m0 + row) * K_ + col8;
    gb[q] = Wdb + (size_t)(n0 + row) * K_ + col8;
  }

  f32x4 acc[4][4] = {};
  const int frow = (lane & 15);
  const int khalf = (lane >> 4);   // 0..3

  int aoff[4], boff[4];
#pragma unroll
  for (int i = 0; i < 4; ++i) {
    const int Ra = wr * 64 + i * 16 + frow;
    const int Rb = wc * 64 + i * 16 + frow;
    aoff[i] = Ra * 32 + (khalf ^ (Ra & 3)) * 8;
    boff[i] = Rb * 32 + (khalf ^ (Rb & 3)) * 8;
  }

#define STAGE_(buf, kt)                                         \
  {                                                             \
    gload_lds16(ga[0] + (kt), &As[buf][tid * 8]);               \
    gload_lds16(ga[1] + (kt), &As[buf][(tid + 256) * 8]);       \
    gload_lds16(gb[0] + (kt), &Bs[buf][tid * 8]);               \
    gload_lds16(gb[1] + (kt), &Bs[buf][(tid + 256) * 8]);       \
  }

  STAGE_(0, 0);
  __syncthreads();

  int cur = 0;
  for (int t = 0; t < K_ / 32; ++t) {
    if (t + 1 < K_ / 32) STAGE_(cur ^ 1, (t + 1) * 32);
    bf16x8 af[4], bfr[4];
#pragma unroll
    for (int i = 0; i < 4; ++i) af[i] = *(const bf16x8*)&As[cur][aoff[i]];
#pragma unroll
    for (int i = 0; i < 4; ++i) bfr[i] = *(const bf16x8*)&Bs[cur][boff[i]];
#pragma unroll
    for (int i = 0; i < 4; ++i)
#pragma unroll
      for (int j = 0; j < 4; ++j)
        acc[i][j] = __builtin_amdgcn_mfma_f32_16x16x32_bf16(af[i], bfr[j], acc[i][j], 0, 0, 0);
    __syncthreads();
    cur ^= 1;
  }
#undef STAGE_

  const int rbase = m0 + wr * 64 + (lane >> 4) * 4;
  const int cbase = n0 + wc * 64 + (lane & 15);
#pragma unroll
  for (int j = 0; j < 4; ++j) {
    const int col = cbase + j * 16;
    const float bias = bd[col];
#pragma unroll
    for (int i = 0; i < 4; ++i) {
      const int row = rbase + i * 16;
#pragma unroll
      for (int r = 0; r < 4; ++r) {
        float z = acc[i][j][r] + bias;
        dtb[(size_t)(row + r) * D_ + col] = (bf16)softplus_f(z);
      }
    }
  }
}

// ---------------- pass 1: per-segment summaries (f32x2-packed math) ----------
__global__ __launch_bounds__(256) void scan_p1(
    const bf16* __restrict__ dtb, const float* __restrict__ Bx,
    const float* __restrict__ A, bf16* __restrict__ hseg,
    float* __restrict__ stot) {
  const int tid = threadIdx.x;
  const int bi = blockIdx.x;
  const int seg = bi & 63;
  const int dtile = (bi >> 6) & 3;
  const int b = bi >> 8;
  const int d = dtile * 256 + tid;
  const int l0 = seg * SLEN_;

  const float* bxp = Bx + ((size_t)b * L_ + l0) * N_;   // wave-uniform

  f32x2 A22[8];
  {
    const float4* ap = (const float4*)(A + (size_t)d * N_);
#pragma unroll
    for (int q = 0; q < 4; ++q) {
      float4 a = ap[q];
      A22[2 * q]     = (f32x2){a.x * LOG2E, a.y * LOG2E};
      A22[2 * q + 1] = (f32x2){a.z * LOG2E, a.w * LOG2E};
    }
  }

  const bf16* dtp = dtb + ((size_t)b * L_ + l0) * D_ + d;
  f32x2 h2[8] = {};
  float s = 0.f;

  float cdt[4];
#pragma unroll
  for (int u = 0; u < 4; ++u) cdt[u] = (float)dtp[(size_t)u * D_];

#define P1_STEP(i, c0)                                                   \
  {                                                                      \
    s += (c0);                                                           \
    const f32x2 c2 = {(c0), (c0)};                                       \
    _Pragma("unroll")                                                    \
    for (int q = 0; q < 4; ++q) {                                        \
      const float4 bv = *(const float4*)(bxp + (i) * N_ + q * 4);        \
      const f32x2 b0 = {bv.x, bv.y}, b1 = {bv.z, bv.w};                  \
      f32x2 g0 = c2 * A22[2 * q];                                        \
      f32x2 g1 = c2 * A22[2 * q + 1];                                    \
      f32x2 e0 = {__builtin_amdgcn_exp2f(g0.x), __builtin_amdgcn_exp2f(g0.y)}; \
      f32x2 e1 = {__builtin_amdgcn_exp2f(g1.x), __builtin_amdgcn_exp2f(g1.y)}; \
      h2[2 * q]     = e0 * h2[2 * q]     + c2 * b0;                      \
      h2[2 * q + 1] = e1 * h2[2 * q + 1] + c2 * b1;                      \
    }                                                                    \
  }

  for (int i0 = 0; i0 < SLEN_ - 4; i0 += 4) {
#pragma unroll
    for (int u = 0; u < 4; ++u) {
      const int i = i0 + u;
      const float c0 = cdt[u];
      cdt[u] = (float)dtp[(size_t)(i + 4) * D_];
      P1_STEP(i, c0);
    }
  }
#pragma unroll
  for (int u = 0; u < 4; ++u) {
    const int i = SLEN_ - 4 + u;
    P1_STEP(i, cdt[u]);
  }
#undef P1_STEP

  bf16* hp = hseg + (((size_t)b * SEG_ + seg) * D_ + d) * N_;
  union { bf16 v[16]; uint4 u[2]; } pk;
#pragma unroll
  for (int m = 0; m < 8; ++m) {
    pk.v[2 * m] = (bf16)h2[m].x;
    pk.v[2 * m + 1] = (bf16)h2[m].y;
  }
  ((uint4*)hp)[0] = pk.u[0];
  ((uint4*)hp)[1] = pk.u[1];
  stot[((size_t)b * SEG_ + seg) * D_ + d] = s;
}

// ---------------- pass 2: exclusive-prefix combine (in-place hseg -> h0) ----
__global__ __launch_bounds__(256) void scan_combine(
    const float* __restrict__ A, bf16* __restrict__ hseg,
    const float* __restrict__ stot) {
  const int tid = threadIdx.x;
  const int bi = blockIdx.x;          // B_ * (D_/16) = 512
  const int b = bi >> 6;
  const int d = (bi & 63) * 16 + (tid >> 4);
  const int n = tid & 15;
  const float A2 = A[(size_t)d * N_ + n] * LOG2E;

  const size_t hbase = ((size_t)b * SEG_ * D_ + d) * N_ + n;
  const size_t sbase = (size_t)b * SEG_ * D_ + d;
  float g = 0.f;
  float hs = (float)hseg[hbase];
  float st = stot[sbase];
  for (int sg = 0; sg < SEG_; ++sg) {
    const int s1 = (sg + 1 < SEG_) ? sg + 1 : sg;
    const float nhs = (float)hseg[hbase + (size_t)s1 * D_ * N_];
    const float nst = stot[sbase + (size_t)s1 * D_];
    hseg[hbase + (size_t)sg * D_ * N_] = (bf16)g;
    g = fmaf(__builtin_amdgcn_exp2f(A2 * st), g, hs);
    hs = nhs; st = nst;
  }
}

// ---------------- pass 3: full recurrence from h0 (f32x2-packed math) --------
__global__ __launch_bounds__(256) void scan_p3(
    const bf16* __restrict__ dtb, const float* __restrict__ Bx,
    const bf16* __restrict__ xb, const float* __restrict__ A,
    const float* __restrict__ C, const float* __restrict__ Dp,
    const bf16* __restrict__ hseg, float* __restrict__ out) {
  const int tid = threadIdx.x;
  const int bi = blockIdx.x;
  const int seg = bi & 63;
  const int dtile = (bi >> 6) & 3;
  const int b = bi >> 8;
  const int d = dtile * 256 + tid;
  const int l0 = seg * SLEN_;

  const float* bxp = Bx + ((size_t)b * L_ + l0) * N_;   // wave-uniform

  f32x2 A22[8], Cv2[8], h2[8];
  {
    const float4* ap = (const float4*)(A + (size_t)d * N_);
    const float4* cp = (const float4*)(C + (size_t)d * N_);
    const bf16* hp = hseg + (((size_t)b * SEG_ + seg) * D_ + d) * N_;
    union { uint4 u[2]; bf16 v[16]; } pk;
    pk.u[0] = ((const uint4*)hp)[0];
    pk.u[1] = ((const uint4*)hp)[1];
#pragma unroll
    for (int q = 0; q < 4; ++q) {
      float4 a = ap[q], c = cp[q];
      A22[2 * q]     = (f32x2){a.x * LOG2E, a.y * LOG2E};
      A22[2 * q + 1] = (f32x2){a.z * LOG2E, a.w * LOG2E};
      Cv2[2 * q]     = (f32x2){c.x, c.y};
      Cv2[2 * q + 1] = (f32x2){c.z, c.w};
    }
#pragma unroll
    for (int m = 0; m < 8; ++m)
      h2[m] = (f32x2){(float)pk.v[2 * m], (float)pk.v[2 * m + 1]};
  }
  const float Dpv = Dp[d];

  const size_t base = ((size_t)b * L_ + l0) * D_ + d;
  const bf16* dtp = dtb + base;
  const bf16* xp = xb + base;
  float* op = out + base;

  float cdt[4], cx[4];
#pragma unroll
  for (int u = 0; u < 4; ++u) {
    cdt[u] = (float)dtp[(size_t)u * D_];
    cx[u]  = (float)xp[(size_t)u * D_];
  }

#define P3_STEP(i, c0, x0)                                               \
  {                                                                      \
    const f32x2 c2 = {(c0), (c0)};                                       \
    f32x2 y2 = {Dpv * (x0), 0.f};                                        \
    _Pragma("unroll")                                                    \
    for (int q = 0; q < 4; ++q) {                                        \
      const float4 bv = *(const float4*)(bxp + (i) * N_ + q * 4);        \
      const f32x2 b0 = {bv.x, bv.y}, b1 = {bv.z, bv.w};                  \
      f32x2 g0 = c2 * A22[2 * q];                                        \
      f32x2 g1 = c2 * A22[2 * q + 1];                                    \
      f32x2 e0 = {__builtin_amdgcn_exp2f(g0.x), __builtin_amdgcn_exp2f(g0.y)}; \
      f32x2 e1 = {__builtin_amdgcn_exp2f(g1.x), __builtin_amdgcn_exp2f(g1.y)}; \
      h2[2 * q]     = e0 * h2[2 * q]     + c2 * b0;                      \
      h2[2 * q + 1] = e1 * h2[2 * q + 1] + c2 * b1;                      \
      y2 = y2 + h2[2 * q] * Cv2[2 * q];                                  \
      y2 = y2 + h2[2 * q + 1] * Cv2[2 * q + 1];                          \
    }                                                                    \
    op[(size_t)(i) * D_] = y2.x + y2.y;                                  \
  }

  for (int i0 = 0; i0 < SLEN_ - 4; i0 += 4) {
#pragma unroll
    for (int u = 0; u < 4; ++u) {
      const int i = i0 + u;
      const float c0 = cdt[u], x0 = cx[u];
      cdt[u] = (float)dtp[(size_t)(i + 4) * D_];
      cx[u]  = (float)xp[(size_t)(i + 4) * D_];
      P3_STEP(i, c0, x0);
    }
  }
#pragma unroll
  for (int u = 0; u < 4; ++u) {
    const int i = SLEN_ - 4 + u;
    P3_STEP(i, cdt[u], cx[u]);
  }
#undef P3_STEP
}

// ---------------- launch ----------------
extern "C" void kernel_launch(void* const* d_in, const int* in_sizes, int n_in,
                              void* d_out, int out_size, void* d_ws, size_t ws_size,
                              hipStream_t stream) {
  const float* x  = (const float*)d_in[0];
  const float* A  = (const float*)d_in[1];
  const float* Wb = (const float*)d_in[2];
  const float* C  = (const float*)d_in[3];
  const float* Dp = (const float*)d_in[4];
  const float* Wd = (const float*)d_in[5];
  const float* bd = (const float*)d_in[6];
  float* out = (float*)d_out;

  char* ws = (char*)d_ws;
  bf16*  dtb  = (bf16*)ws;                                  // 32 MB [M,D] bf16
  bf16*  xb   = (bf16*)(ws + (size_t)33554432);             // 32 MB [M,K] bf16
  bf16*  wdb  = (bf16*)(ws + (size_t)67108864);             //  2 MB [D,K] bf16
  bf16*  wbb  = (bf16*)(ws + (size_t)69206016);             // 32 KB [16,K] bf16
  float* bx   = (float*)(ws + (size_t)69238784);            //  1 MB [M,16] f32
  bf16*  hseg = (bf16*)(ws + (size_t)70287360);             // 16 MB [B][SEG][D][N] bf16
  float* stot = (float*)(ws + (size_t)87064576);            //  2 MB [B][SEG][D] f32

  cvt_wdwb<<<1040, 256, 0, stream>>>(Wd, Wb, wdb, wbb);
  prep_x<<<dim3(M_ / 16), 256, 0, stream>>>(x, wbb, xb, bx);
  gemm_dt<<<dim3((M_ / 128) * (D_ / 128)), 256, 0, stream>>>(xb, wdb, bd, dtb);
  scan_p1<<<dim3(B_ * 4 * SEG_), 256, 0, stream>>>(dtb, bx, A, hseg, stot);
  scan_combine<<<dim3(B_ * (D_ / 16)), 256, 0, stream>>>(A, hseg, stot);
  scan_p3<<<dim3(B_ * 4 * SEG_), 256, 0, stream>>>(dtb, bx, xb, A, C, Dp, hseg, out);
}

// Round 14
// 156.651 us; speedup vs baseline: 1.1632x; 1.0555x over previous
//
#include <hip/hip_runtime.h>
#include <hip/hip_bf16.h>
#include <stdint.h>

#define B_ 8
#define L_ 2048
#define D_ 1024
#define N_ 16
#define M_ (B_ * L_)   // 16384 rows
#define K_ D_          // 1024
#define SEG_ 64
#define SLEN_ (L_ / SEG_)   // 32
#define LOG2E 1.44269504088896341f

typedef __bf16 bf16;
typedef __bf16 bf16x8 __attribute__((ext_vector_type(8)));
typedef float f32x4 __attribute__((ext_vector_type(4)));
typedef float f32x2 __attribute__((ext_vector_type(2)));

// ---------------- prep_x: blocks <1024: x->bf16 + Bx MFMA; >=1024: Wd cvt ----
__global__ __launch_bounds__(256) void prep_x(const float* __restrict__ x,
                                              const float* __restrict__ Wb,
                                              const float* __restrict__ Wd,
                                              bf16* __restrict__ xb,
                                              bf16* __restrict__ wdb,
                                              float* __restrict__ Bx) {
  const int bi = blockIdx.x;
  if (bi >= 1024) {            // Wd: 1M elems = 262144 float4 over 1024 blocks
    const int i = (bi - 1024) * 256 + threadIdx.x;
    float4 v = ((const float4*)Wd)[i];
    union { bf16 h[4]; uint2 u; } p;
    p.h[0] = (bf16)v.x; p.h[1] = (bf16)v.y; p.h[2] = (bf16)v.z; p.h[3] = (bf16)v.w;
    ((uint2*)wdb)[i] = p.u;
    return;
  }
  const int lane = threadIdx.x & 63;
  const int wave = threadIdx.x >> 6;
  const int row0 = bi * 16;
  const int fr = lane & 15;
  const int kg = (lane >> 4) * 8;
  const int k0 = wave * 256;
  const float* gx = x + (size_t)(row0 + fr) * K_ + k0 + kg;
  const float* gw = Wb + (size_t)fr * K_ + k0 + kg;
  bf16* gxb = xb + (size_t)(row0 + fr) * K_ + k0 + kg;

  f32x4 acc = {};
#pragma unroll 8
  for (int kt = 0; kt < 8; ++kt) {
    float4 v0 = *(const float4*)(gx + kt * 32);
    float4 v1 = *(const float4*)(gx + kt * 32 + 4);
    float4 w0 = *(const float4*)(gw + kt * 32);
    float4 w1 = *(const float4*)(gw + kt * 32 + 4);
    union { bf16 h[8]; bf16x8 v; uint4 u; } p;
    p.h[0] = (bf16)v0.x; p.h[1] = (bf16)v0.y; p.h[2] = (bf16)v0.z; p.h[3] = (bf16)v0.w;
    p.h[4] = (bf16)v1.x; p.h[5] = (bf16)v1.y; p.h[6] = (bf16)v1.z; p.h[7] = (bf16)v1.w;
    *(uint4*)(gxb + kt * 32) = p.u;
    union { bf16 h[8]; bf16x8 v; } wp;
    wp.h[0] = (bf16)w0.x; wp.h[1] = (bf16)w0.y; wp.h[2] = (bf16)w0.z; wp.h[3] = (bf16)w0.w;
    wp.h[4] = (bf16)w1.x; wp.h[5] = (bf16)w1.y; wp.h[6] = (bf16)w1.z; wp.h[7] = (bf16)w1.w;
    acc = __builtin_amdgcn_mfma_f32_16x16x32_bf16(p.v, wp.v, acc, 0, 0, 0);
  }

  __shared__ float red[4][16][17];   // +1 pad breaks ds bank conflicts
  const int orow = (lane >> 4) * 4, ocol = fr;
#pragma unroll
  for (int r = 0; r < 4; ++r) red[wave][orow + r][ocol] = acc[r];
  __syncthreads();
  const int rr = threadIdx.x >> 4, cc = threadIdx.x & 15;
  const float s = red[0][rr][cc] + red[1][rr][cc] + red[2][rr][cc] + red[3][rr][cc];
  Bx[(size_t)(row0 + rr) * N_ + cc] = s;
}

// ---------------- async global->LDS helper (16B) ----------------
__device__ inline void gload_lds16(const bf16* g, bf16* l) {
  __builtin_amdgcn_global_load_lds(
      (const __attribute__((address_space(1))) void*)g,
      (__attribute__((address_space(3))) void*)l, 16, 0, 0);
}

__device__ inline float softplus_f(float z) {
  return fmaxf(z, 0.f) + __logf(1.f + __expf(-fabsf(z)));
}

// ---------------- dt GEMM: dtb = bf16(softplus(Xb @ Wdb^T + bd)) ----------------
// R8-proven 2-phase: 128x128 tile, BK=32, 4 waves, double-buffered, both-sides
// LDS XOR-swizzle, XCD-chunked block swizzle. 54.5 us / 630 TF (2-phase ceiling).
__global__ __launch_bounds__(256) void gemm_dt(const bf16* __restrict__ Xb,
                                               const bf16* __restrict__ Wdb,
                                               const float* __restrict__ bd,
                                               bf16* __restrict__ dtb) {
  __shared__ bf16 As[2][128 * 32];
  __shared__ bf16 Bs[2][128 * 32];
  const int tid = threadIdx.x;
  const int lane = tid & 63;
  const int wave = tid >> 6;
  const int wr = wave >> 1, wc = wave & 1;
  const int virt = (blockIdx.x & 7) * 128 + (blockIdx.x >> 3);
  const int mt = virt >> 3, nt = virt & 7;
  const int m0 = mt * 128, n0 = nt * 128;

  const bf16* ga[2];
  const bf16* gb[2];
#pragma unroll
  for (int q = 0; q < 2; ++q) {
    const int c = tid + 256 * q;
    const int row = c >> 2;
    const int col8 = ((c & 3) ^ (row & 3)) * 8;
    ga[q] = Xb + (size_t)(m0 + row) * K_ + col8;
    gb[q] = Wdb + (size_t)(n0 + row) * K_ + col8;
  }

  f32x4 acc[4][4] = {};
  const int frow = (lane & 15);
  const int khalf = (lane >> 4);   // 0..3

  int aoff[4], boff[4];
#pragma unroll
  for (int i = 0; i < 4; ++i) {
    const int Ra = wr * 64 + i * 16 + frow;
    const int Rb = wc * 64 + i * 16 + frow;
    aoff[i] = Ra * 32 + (khalf ^ (Ra & 3)) * 8;
    boff[i] = Rb * 32 + (khalf ^ (Rb & 3)) * 8;
  }

#define STAGE_(buf, kt)                                         \
  {                                                             \
    gload_lds16(ga[0] + (kt), &As[buf][tid * 8]);               \
    gload_lds16(ga[1] + (kt), &As[buf][(tid + 256) * 8]);       \
    gload_lds16(gb[0] + (kt), &Bs[buf][tid * 8]);               \
    gload_lds16(gb[1] + (kt), &Bs[buf][(tid + 256) * 8]);       \
  }

  STAGE_(0, 0);
  __syncthreads();

  int cur = 0;
  for (int t = 0; t < K_ / 32; ++t) {
    if (t + 1 < K_ / 32) STAGE_(cur ^ 1, (t + 1) * 32);
    bf16x8 af[4], bfr[4];
#pragma unroll
    for (int i = 0; i < 4; ++i) af[i] = *(const bf16x8*)&As[cur][aoff[i]];
#pragma unroll
    for (int i = 0; i < 4; ++i) bfr[i] = *(const bf16x8*)&Bs[cur][boff[i]];
#pragma unroll
    for (int i = 0; i < 4; ++i)
#pragma unroll
      for (int j = 0; j < 4; ++j)
        acc[i][j] = __builtin_amdgcn_mfma_f32_16x16x32_bf16(af[i], bfr[j], acc[i][j], 0, 0, 0);
    __syncthreads();
    cur ^= 1;
  }
#undef STAGE_

  const int rbase = m0 + wr * 64 + (lane >> 4) * 4;
  const int cbase = n0 + wc * 64 + (lane & 15);
#pragma unroll
  for (int j = 0; j < 4; ++j) {
    const int col = cbase + j * 16;
    const float bias = bd[col];
#pragma unroll
    for (int i = 0; i < 4; ++i) {
      const int row = rbase + i * 16;
#pragma unroll
      for (int r = 0; r < 4; ++r) {
        float z = acc[i][j][r] + bias;
        dtb[(size_t)(row + r) * D_ + col] = (bf16)softplus_f(z);
      }
    }
  }
}

// ---------------- pass 1: per-segment summaries (packed math, bx prefetch) ----
__global__ __launch_bounds__(256) void scan_p1(
    const bf16* __restrict__ dtb, const float* __restrict__ Bx,
    const float* __restrict__ A, bf16* __restrict__ hseg,
    float* __restrict__ stot) {
  const int tid = threadIdx.x;
  const int bi = blockIdx.x;
  const int seg = bi & 63;
  const int dtile = (bi >> 6) & 3;
  const int b = bi >> 8;
  const int d = dtile * 256 + tid;
  const int l0 = seg * SLEN_;

  const float* bxp = Bx + ((size_t)b * L_ + l0) * N_;   // wave-uniform

  f32x2 A22[8];
  {
    const float4* ap = (const float4*)(A + (size_t)d * N_);
#pragma unroll
    for (int q = 0; q < 4; ++q) {
      float4 a = ap[q];
      A22[2 * q]     = (f32x2){a.x * LOG2E, a.y * LOG2E};
      A22[2 * q + 1] = (f32x2){a.z * LOG2E, a.w * LOG2E};
    }
  }

  const bf16* dtp = dtb + ((size_t)b * L_ + l0) * D_ + d;
  f32x2 h2[8] = {};
  float s = 0.f;

  float cdt[4];
#pragma unroll
  for (int u = 0; u < 4; ++u) cdt[u] = (float)dtp[(size_t)u * D_];

  float4 nb[4];
#pragma unroll
  for (int q = 0; q < 4; ++q) nb[q] = *(const float4*)(bxp + q * 4);

#define P1_STEP(i, ip1, c0)                                              \
  {                                                                      \
    s += (c0);                                                           \
    const f32x2 c2 = {(c0), (c0)};                                       \
    float4 tb[4];                                                        \
    _Pragma("unroll")                                                    \
    for (int q = 0; q < 4; ++q)                                          \
      tb[q] = *(const float4*)(bxp + (ip1) * N_ + q * 4);                \
    _Pragma("unroll")                                                    \
    for (int q = 0; q < 4; ++q) {                                        \
      const f32x2 b0 = {nb[q].x, nb[q].y}, b1 = {nb[q].z, nb[q].w};      \
      f32x2 g0 = c2 * A22[2 * q];                                        \
      f32x2 g1 = c2 * A22[2 * q + 1];                                    \
      f32x2 e0 = {__builtin_amdgcn_exp2f(g0.x), __builtin_amdgcn_exp2f(g0.y)}; \
      f32x2 e1 = {__builtin_amdgcn_exp2f(g1.x), __builtin_amdgcn_exp2f(g1.y)}; \
      h2[2 * q]     = e0 * h2[2 * q]     + c2 * b0;                      \
      h2[2 * q + 1] = e1 * h2[2 * q + 1] + c2 * b1;                      \
    }                                                                    \
    _Pragma("unroll")                                                    \
    for (int q = 0; q < 4; ++q) nb[q] = tb[q];                           \
  }

  for (int i0 = 0; i0 < SLEN_ - 4; i0 += 4) {
#pragma unroll
    for (int u = 0; u < 4; ++u) {
      const int i = i0 + u;
      const float c0 = cdt[u];
      cdt[u] = (float)dtp[(size_t)(i + 4) * D_];
      P1_STEP(i, i + 1, c0);
    }
  }
#pragma unroll
  for (int u = 0; u < 4; ++u) {
    const int i = SLEN_ - 4 + u;
    const int ip1 = (u < 3) ? i + 1 : i;
    P1_STEP(i, ip1, cdt[u]);
  }
#undef P1_STEP

  bf16* hp = hseg + (((size_t)b * SEG_ + seg) * D_ + d) * N_;
  union { bf16 v[16]; uint4 u[2]; } pk;
#pragma unroll
  for (int m = 0; m < 8; ++m) {
    pk.v[2 * m] = (bf16)h2[m].x;
    pk.v[2 * m + 1] = (bf16)h2[m].y;
  }
  ((uint4*)hp)[0] = pk.u[0];
  ((uint4*)hp)[1] = pk.u[1];
  stot[((size_t)b * SEG_ + seg) * D_ + d] = s;
}

// ---------------- pass 2: exclusive-prefix combine (in-place hseg -> h0) ----
__global__ __launch_bounds__(256) void scan_combine(
    const float* __restrict__ A, bf16* __restrict__ hseg,
    const float* __restrict__ stot) {
  const int tid = threadIdx.x;
  const int bi = blockIdx.x;          // B_ * (D_/16) = 512
  const int b = bi >> 6;
  const int d = (bi & 63) * 16 + (tid >> 4);
  const int n = tid & 15;
  const float A2 = A[(size_t)d * N_ + n] * LOG2E;

  const size_t hbase = ((size_t)b * SEG_ * D_ + d) * N_ + n;
  const size_t sbase = (size_t)b * SEG_ * D_ + d;
  float g = 0.f;
  float hs = (float)hseg[hbase];
  float st = stot[sbase];
  for (int sg = 0; sg < SEG_; ++sg) {
    const int s1 = (sg + 1 < SEG_) ? sg + 1 : sg;
    const float nhs = (float)hseg[hbase + (size_t)s1 * D_ * N_];
    const float nst = stot[sbase + (size_t)s1 * D_];
    hseg[hbase + (size_t)sg * D_ * N_] = (bf16)g;
    g = fmaf(__builtin_amdgcn_exp2f(A2 * st), g, hs);
    hs = nhs; st = nst;
  }
}

// ---------------- pass 3: recurrence from h0 (packed math, bx prefetch) ------
__global__ __launch_bounds__(256) void scan_p3(
    const bf16* __restrict__ dtb, const float* __restrict__ Bx,
    const bf16* __restrict__ xb, const float* __restrict__ A,
    const float* __restrict__ C, const float* __restrict__ Dp,
    const bf16* __restrict__ hseg, float* __restrict__ out) {
  const int tid = threadIdx.x;
  const int bi = blockIdx.x;
  const int seg = bi & 63;
  const int dtile = (bi >> 6) & 3;
  const int b = bi >> 8;
  const int d = dtile * 256 + tid;
  const int l0 = seg * SLEN_;

  const float* bxp = Bx + ((size_t)b * L_ + l0) * N_;   // wave-uniform

  f32x2 A22[8], Cv2[8], h2[8];
  {
    const float4* ap = (const float4*)(A + (size_t)d * N_);
    const float4* cp = (const float4*)(C + (size_t)d * N_);
    const bf16* hp = hseg + (((size_t)b * SEG_ + seg) * D_ + d) * N_;
    union { uint4 u[2]; bf16 v[16]; } pk;
    pk.u[0] = ((const uint4*)hp)[0];
    pk.u[1] = ((const uint4*)hp)[1];
#pragma unroll
    for (int q = 0; q < 4; ++q) {
      float4 a = ap[q], c = cp[q];
      A22[2 * q]     = (f32x2){a.x * LOG2E, a.y * LOG2E};
      A22[2 * q + 1] = (f32x2){a.z * LOG2E, a.w * LOG2E};
      Cv2[2 * q]     = (f32x2){c.x, c.y};
      Cv2[2 * q + 1] = (f32x2){c.z, c.w};
    }
#pragma unroll
    for (int m = 0; m < 8; ++m)
      h2[m] = (f32x2){(float)pk.v[2 * m], (float)pk.v[2 * m + 1]};
  }
  const float Dpv = Dp[d];

  const size_t base = ((size_t)b * L_ + l0) * D_ + d;
  const bf16* dtp = dtb + base;
  const bf16* xp = xb + base;
  float* op = out + base;

  float cdt[4], cx[4];
#pragma unroll
  for (int u = 0; u < 4; ++u) {
    cdt[u] = (float)dtp[(size_t)u * D_];
    cx[u]  = (float)xp[(size_t)u * D_];
  }

  float4 nb[4];
#pragma unroll
  for (int q = 0; q < 4; ++q) nb[q] = *(const float4*)(bxp + q * 4);

#define P3_STEP(i, ip1, c0, x0)                                          \
  {                                                                      \
    const f32x2 c2 = {(c0), (c0)};                                       \
    f32x2 y2 = {Dpv * (x0), 0.f};                                        \
    float4 tb[4];                                                        \
    _Pragma("unroll")                                                    \
    for (int q = 0; q < 4; ++q)                                          \
      tb[q] = *(const float4*)(bxp + (ip1) * N_ + q * 4);                \
    _Pragma("unroll")                                                    \
    for (int q = 0; q < 4; ++q) {                                        \
      const f32x2 b0 = {nb[q].x, nb[q].y}, b1 = {nb[q].z, nb[q].w};      \
      f32x2 g0 = c2 * A22[2 * q];                                        \
      f32x2 g1 = c2 * A22[2 * q + 1];                                    \
      f32x2 e0 = {__builtin_amdgcn_exp2f(g0.x), __builtin_amdgcn_exp2f(g0.y)}; \
      f32x2 e1 = {__builtin_amdgcn_exp2f(g1.x), __builtin_amdgcn_exp2f(g1.y)}; \
      h2[2 * q]     = e0 * h2[2 * q]     + c2 * b0;                      \
      h2[2 * q + 1] = e1 * h2[2 * q + 1] + c2 * b1;                      \
      y2 = y2 + h2[2 * q] * Cv2[2 * q];                                  \
      y2 = y2 + h2[2 * q + 1] * Cv2[2 * q + 1];                          \
    }                                                                    \
    _Pragma("unroll")                                                    \
    for (int q = 0; q < 4; ++q) nb[q] = tb[q];                           \
    op[(size_t)(i) * D_] = y2.x + y2.y;                                  \
  }

  for (int i0 = 0; i0 < SLEN_ - 4; i0 += 4) {
#pragma unroll
    for (int u = 0; u < 4; ++u) {
      const int i = i0 + u;
      const float c0 = cdt[u], x0 = cx[u];
      cdt[u] = (float)dtp[(size_t)(i + 4) * D_];
      cx[u]  = (float)xp[(size_t)(i + 4) * D_];
      P3_STEP(i, i + 1, c0, x0);
    }
  }
#pragma unroll
  for (int u = 0; u < 4; ++u) {
    const int i = SLEN_ - 4 + u;
    const int ip1 = (u < 3) ? i + 1 : i;
    P3_STEP(i, ip1, cdt[u], cx[u]);
  }
#undef P3_STEP
}

// ---------------- launch ----------------
extern "C" void kernel_launch(void* const* d_in, const int* in_sizes, int n_in,
                              void* d_out, int out_size, void* d_ws, size_t ws_size,
                              hipStream_t stream) {
  const float* x  = (const float*)d_in[0];
  const float* A  = (const float*)d_in[1];
  const float* Wb = (const float*)d_in[2];
  const float* C  = (const float*)d_in[3];
  const float* Dp = (const float*)d_in[4];
  const float* Wd = (const float*)d_in[5];
  const float* bd = (const float*)d_in[6];
  float* out = (float*)d_out;

  char* ws = (char*)d_ws;
  bf16*  dtb  = (bf16*)ws;                                  // 32 MB [M,D] bf16
  bf16*  xb   = (bf16*)(ws + (size_t)33554432);             // 32 MB [M,K] bf16
  bf16*  wdb  = (bf16*)(ws + (size_t)67108864);             //  2 MB [D,K] bf16
  float* bx   = (float*)(ws + (size_t)69206016);            //  1 MB [M,16] f32
  bf16*  hseg = (bf16*)(ws + (size_t)70254592);             // 16 MB [B][SEG][D][N] bf16
  float* stot = (float*)(ws + (size_t)87031808);            //  2 MB [B][SEG][D] f32

  prep_x<<<dim3(2048), 256, 0, stream>>>(x, Wb, Wd, xb, wdb, bx);
  gemm_dt<<<dim3((M_ / 128) * (D_ / 128)), 256, 0, stream>>>(xb, wdb, bd, dtb);
  scan_p1<<<dim3(B_ * 4 * SEG_), 256, 0, stream>>>(dtb, bx, A, hseg, stot);
  scan_combine<<<dim3(B_ * (D_ / 16)), 256, 0, stream>>>(A, hseg, stot);
  scan_p3<<<dim3(B_ * 4 * SEG_), 256, 0, stream>>>(dtb, bx, xb, A, C, Dp, hseg, out);
}

// Round 16
// 155.700 us; speedup vs baseline: 1.1703x; 1.0061x over previous
//
#include <hip/hip_runtime.h>
#include <hip/hip_bf16.h>
#include <stdint.h>

#define B_ 8
#define L_ 2048
#define D_ 1024
#define N_ 16
#define M_ (B_ * L_)   // 16384 rows
#define K_ D_          // 1024
#define SEG_ 64
#define SLEN_ (L_ / SEG_)   // 32
#define LOG2E 1.44269504088896341f

typedef __bf16 bf16;
typedef __bf16 bf16x8 __attribute__((ext_vector_type(8)));
typedef float f32x4 __attribute__((ext_vector_type(4)));
typedef float f32x2 __attribute__((ext_vector_type(2)));

// ---------------- prep_x: blocks <1024: x->bf16 + Bx MFMA; >=1024: Wd cvt ----
__global__ __launch_bounds__(256) void prep_x(const float* __restrict__ x,
                                              const float* __restrict__ Wb,
                                              const float* __restrict__ Wd,
                                              bf16* __restrict__ xb,
                                              bf16* __restrict__ wdb,
                                              float* __restrict__ Bx) {
  const int bi = blockIdx.x;
  if (bi >= 1024) {            // Wd: 1M elems = 262144 float4 over 1024 blocks
    const int i = (bi - 1024) * 256 + threadIdx.x;
    float4 v = ((const float4*)Wd)[i];
    union { bf16 h[4]; uint2 u; } p;
    p.h[0] = (bf16)v.x; p.h[1] = (bf16)v.y; p.h[2] = (bf16)v.z; p.h[3] = (bf16)v.w;
    ((uint2*)wdb)[i] = p.u;
    return;
  }
  const int lane = threadIdx.x & 63;
  const int wave = threadIdx.x >> 6;
  const int row0 = bi * 16;
  const int fr = lane & 15;
  const int kg = (lane >> 4) * 8;
  const int k0 = wave * 256;
  const float* gx = x + (size_t)(row0 + fr) * K_ + k0 + kg;
  const float* gw = Wb + (size_t)fr * K_ + k0 + kg;
  bf16* gxb = xb + (size_t)(row0 + fr) * K_ + k0 + kg;

  f32x4 acc = {};
#pragma unroll 8
  for (int kt = 0; kt < 8; ++kt) {
    float4 v0 = *(const float4*)(gx + kt * 32);
    float4 v1 = *(const float4*)(gx + kt * 32 + 4);
    float4 w0 = *(const float4*)(gw + kt * 32);
    float4 w1 = *(const float4*)(gw + kt * 32 + 4);
    union { bf16 h[8]; bf16x8 v; uint4 u; } p;
    p.h[0] = (bf16)v0.x; p.h[1] = (bf16)v0.y; p.h[2] = (bf16)v0.z; p.h[3] = (bf16)v0.w;
    p.h[4] = (bf16)v1.x; p.h[5] = (bf16)v1.y; p.h[6] = (bf16)v1.z; p.h[7] = (bf16)v1.w;
    *(uint4*)(gxb + kt * 32) = p.u;
    union { bf16 h[8]; bf16x8 v; } wp;
    wp.h[0] = (bf16)w0.x; wp.h[1] = (bf16)w0.y; wp.h[2] = (bf16)w0.z; wp.h[3] = (bf16)w0.w;
    wp.h[4] = (bf16)w1.x; wp.h[5] = (bf16)w1.y; wp.h[6] = (bf16)w1.z; wp.h[7] = (bf16)w1.w;
    acc = __builtin_amdgcn_mfma_f32_16x16x32_bf16(p.v, wp.v, acc, 0, 0, 0);
  }

  __shared__ float red[4][16][17];
  const int orow = (lane >> 4) * 4, ocol = fr;
#pragma unroll
  for (int r = 0; r < 4; ++r) red[wave][orow + r][ocol] = acc[r];
  __syncthreads();
  const int rr = threadIdx.x >> 4, cc = threadIdx.x & 15;
  const float s = red[0][rr][cc] + red[1][rr][cc] + red[2][rr][cc] + red[3][rr][cc];
  Bx[(size_t)(row0 + rr) * N_ + cc] = s;
}

// ---------------- async global->LDS helper (16B) ----------------
__device__ inline void gload_lds16(const bf16* g, bf16* l) {
  __builtin_amdgcn_global_load_lds(
      (const __attribute__((address_space(1))) void*)g,
      (__attribute__((address_space(3))) void*)l, 16, 0, 0);
}

__device__ inline float softplus_f(float z) {
  return fmaxf(z, 0.f) + __logf(1.f + __expf(-fabsf(z)));
}

// ---------------- dt GEMM: dtb = bf16(softplus(Xb @ Wdb^T + bd)) ----------------
// R8-proven 2-phase: 128x128 tile, BK=32, 4 waves, double-buffered, both-sides
// LDS XOR-swizzle, XCD-chunked block swizzle. 54.5 us / 630 TF (2-phase ceiling).
// 8-phase abandoned after R9/R11/R15: no win, and R15's read-before-barrier
// reordering races (reads of a buffer vs next-tile global_load_lds overwrite).
__global__ __launch_bounds__(256) void gemm_dt(const bf16* __restrict__ Xb,
                                               const bf16* __restrict__ Wdb,
                                               const float* __restrict__ bd,
                                               bf16* __restrict__ dtb) {
  __shared__ bf16 As[2][128 * 32];
  __shared__ bf16 Bs[2][128 * 32];
  const int tid = threadIdx.x;
  const int lane = tid & 63;
  const int wave = tid >> 6;
  const int wr = wave >> 1, wc = wave & 1;
  const int virt = (blockIdx.x & 7) * 128 + (blockIdx.x >> 3);
  const int mt = virt >> 3, nt = virt & 7;
  const int m0 = mt * 128, n0 = nt * 128;

  const bf16* ga[2];
  const bf16* gb[2];
#pragma unroll
  for (int q = 0; q < 2; ++q) {
    const int c = tid + 256 * q;
    const int row = c >> 2;
    const int col8 = ((c & 3) ^ (row & 3)) * 8;
    ga[q] = Xb + (size_t)(m0 + row) * K_ + col8;
    gb[q] = Wdb + (size_t)(n0 + row) * K_ + col8;
  }

  f32x4 acc[4][4] = {};
  const int frow = (lane & 15);
  const int khalf = (lane >> 4);   // 0..3

  int aoff[4], boff[4];
#pragma unroll
  for (int i = 0; i < 4; ++i) {
    const int Ra = wr * 64 + i * 16 + frow;
    const int Rb = wc * 64 + i * 16 + frow;
    aoff[i] = Ra * 32 + (khalf ^ (Ra & 3)) * 8;
    boff[i] = Rb * 32 + (khalf ^ (Rb & 3)) * 8;
  }

#define STAGE_(buf, kt)                                         \
  {                                                             \
    gload_lds16(ga[0] + (kt), &As[buf][tid * 8]);               \
    gload_lds16(ga[1] + (kt), &As[buf][(tid + 256) * 8]);       \
    gload_lds16(gb[0] + (kt), &Bs[buf][tid * 8]);               \
    gload_lds16(gb[1] + (kt), &Bs[buf][(tid + 256) * 8]);       \
  }

  STAGE_(0, 0);
  __syncthreads();

  int cur = 0;
  for (int t = 0; t < K_ / 32; ++t) {
    if (t + 1 < K_ / 32) STAGE_(cur ^ 1, (t + 1) * 32);
    bf16x8 af[4], bfr[4];
#pragma unroll
    for (int i = 0; i < 4; ++i) af[i] = *(const bf16x8*)&As[cur][aoff[i]];
#pragma unroll
    for (int i = 0; i < 4; ++i) bfr[i] = *(const bf16x8*)&Bs[cur][boff[i]];
#pragma unroll
    for (int i = 0; i < 4; ++i)
#pragma unroll
      for (int j = 0; j < 4; ++j)
        acc[i][j] = __builtin_amdgcn_mfma_f32_16x16x32_bf16(af[i], bfr[j], acc[i][j], 0, 0, 0);
    __syncthreads();
    cur ^= 1;
  }
#undef STAGE_

  const int rbase = m0 + wr * 64 + (lane >> 4) * 4;
  const int cbase = n0 + wc * 64 + (lane & 15);
#pragma unroll
  for (int j = 0; j < 4; ++j) {
    const int col = cbase + j * 16;
    const float bias = bd[col];
#pragma unroll
    for (int i = 0; i < 4; ++i) {
      const int row = rbase + i * 16;
#pragma unroll
      for (int r = 0; r < 4; ++r) {
        float z = acc[i][j][r] + bias;
        dtb[(size_t)(row + r) * D_ + col] = (bf16)softplus_f(z);
      }
    }
  }
}

// ---------------- pass 1: per-segment summaries (packed math, bx prefetch) ----
__global__ __launch_bounds__(256) void scan_p1(
    const bf16* __restrict__ dtb, const float* __restrict__ Bx,
    const float* __restrict__ A, bf16* __restrict__ hseg,
    float* __restrict__ stot) {
  const int tid = threadIdx.x;
  const int bi = blockIdx.x;
  const int seg = bi & 63;
  const int dtile = (bi >> 6) & 3;
  const int b = bi >> 8;
  const int d = dtile * 256 + tid;
  const int l0 = seg * SLEN_;

  const float* bxp = Bx + ((size_t)b * L_ + l0) * N_;   // wave-uniform

  f32x2 A22[8];
  {
    const float4* ap = (const float4*)(A + (size_t)d * N_);
#pragma unroll
    for (int q = 0; q < 4; ++q) {
      float4 a = ap[q];
      A22[2 * q]     = (f32x2){a.x * LOG2E, a.y * LOG2E};
      A22[2 * q + 1] = (f32x2){a.z * LOG2E, a.w * LOG2E};
    }
  }

  const bf16* dtp = dtb + ((size_t)b * L_ + l0) * D_ + d;
  f32x2 h2[8] = {};
  float s = 0.f;

  float cdt[4];
#pragma unroll
  for (int u = 0; u < 4; ++u) cdt[u] = (float)dtp[(size_t)u * D_];

  float4 nb[4];
#pragma unroll
  for (int q = 0; q < 4; ++q) nb[q] = *(const float4*)(bxp + q * 4);

#define P1_STEP(i, ip1, c0)                                              \
  {                                                                      \
    s += (c0);                                                           \
    const f32x2 c2 = {(c0), (c0)};                                       \
    float4 tb[4];                                                        \
    _Pragma("unroll")                                                    \
    for (int q = 0; q < 4; ++q)                                          \
      tb[q] = *(const float4*)(bxp + (ip1) * N_ + q * 4);                \
    _Pragma("unroll")                                                    \
    for (int q = 0; q < 4; ++q) {                                        \
      const f32x2 b0 = {nb[q].x, nb[q].y}, b1 = {nb[q].z, nb[q].w};      \
      f32x2 g0 = c2 * A22[2 * q];                                        \
      f32x2 g1 = c2 * A22[2 * q + 1];                                    \
      f32x2 e0 = {__builtin_amdgcn_exp2f(g0.x), __builtin_amdgcn_exp2f(g0.y)}; \
      f32x2 e1 = {__builtin_amdgcn_exp2f(g1.x), __builtin_amdgcn_exp2f(g1.y)}; \
      h2[2 * q]     = e0 * h2[2 * q]     + c2 * b0;                      \
      h2[2 * q + 1] = e1 * h2[2 * q + 1] + c2 * b1;                      \
    }                                                                    \
    _Pragma("unroll")                                                    \
    for (int q = 0; q < 4; ++q) nb[q] = tb[q];                           \
  }

  for (int i0 = 0; i0 < SLEN_ - 4; i0 += 4) {
#pragma unroll
    for (int u = 0; u < 4; ++u) {
      const int i = i0 + u;
      const float c0 = cdt[u];
      cdt[u] = (float)dtp[(size_t)(i + 4) * D_];
      P1_STEP(i, i + 1, c0);
    }
  }
#pragma unroll
  for (int u = 0; u < 4; ++u) {
    const int i = SLEN_ - 4 + u;
    const int ip1 = (u < 3) ? i + 1 : i;
    P1_STEP(i, ip1, cdt[u]);
  }
#undef P1_STEP

  bf16* hp = hseg + (((size_t)b * SEG_ + seg) * D_ + d) * N_;
  union { bf16 v[16]; uint4 u[2]; } pk;
#pragma unroll
  for (int m = 0; m < 8; ++m) {
    pk.v[2 * m] = (bf16)h2[m].x;
    pk.v[2 * m + 1] = (bf16)h2[m].y;
  }
  ((uint4*)hp)[0] = pk.u[0];
  ((uint4*)hp)[1] = pk.u[1];
  stot[((size_t)b * SEG_ + seg) * D_ + d] = s;
}

// ---------------- pass 2: exclusive-prefix combine (in-place hseg -> h0) ----
__global__ __launch_bounds__(256) void scan_combine(
    const float* __restrict__ A, bf16* __restrict__ hseg,
    const float* __restrict__ stot) {
  const int tid = threadIdx.x;
  const int bi = blockIdx.x;          // B_ * (D_/16) = 512
  const int b = bi >> 6;
  const int d = (bi & 63) * 16 + (tid >> 4);
  const int n = tid & 15;
  const float A2 = A[(size_t)d * N_ + n] * LOG2E;

  const size_t hbase = ((size_t)b * SEG_ * D_ + d) * N_ + n;
  const size_t sbase = (size_t)b * SEG_ * D_ + d;
  float g = 0.f;
  float hs = (float)hseg[hbase];
  float st = stot[sbase];
  for (int sg = 0; sg < SEG_; ++sg) {
    const int s1 = (sg + 1 < SEG_) ? sg + 1 : sg;
    const float nhs = (float)hseg[hbase + (size_t)s1 * D_ * N_];
    const float nst = stot[sbase + (size_t)s1 * D_];
    hseg[hbase + (size_t)sg * D_ * N_] = (bf16)g;
    g = fmaf(__builtin_amdgcn_exp2f(A2 * st), g, hs);
    hs = nhs; st = nst;
  }
}

// ---------------- pass 3: recurrence from h0 (packed math, bx prefetch,
//                  cross-step exp2 pipeline: e2 for step i+1 computed during
//                  step i's h/y FMA chain — exp2 depends only on prefetched dt) -
__global__ __launch_bounds__(256) void scan_p3(
    const bf16* __restrict__ dtb, const float* __restrict__ Bx,
    const bf16* __restrict__ xb, const float* __restrict__ A,
    const float* __restrict__ C, const float* __restrict__ Dp,
    const bf16* __restrict__ hseg, float* __restrict__ out) {
  const int tid = threadIdx.x;
  const int bi = blockIdx.x;
  const int seg = bi & 63;
  const int dtile = (bi >> 6) & 3;
  const int b = bi >> 8;
  const int d = dtile * 256 + tid;
  const int l0 = seg * SLEN_;

  const float* bxp = Bx + ((size_t)b * L_ + l0) * N_;   // wave-uniform

  f32x2 A22[8], Cv2[8], h2[8];
  {
    const float4* ap = (const float4*)(A + (size_t)d * N_);
    const float4* cp = (const float4*)(C + (size_t)d * N_);
    const bf16* hp = hseg + (((size_t)b * SEG_ + seg) * D_ + d) * N_;
    union { uint4 u[2]; bf16 v[16]; } pk;
    pk.u[0] = ((const uint4*)hp)[0];
    pk.u[1] = ((const uint4*)hp)[1];
#pragma unroll
    for (int q = 0; q < 4; ++q) {
      float4 a = ap[q], c = cp[q];
      A22[2 * q]     = (f32x2){a.x * LOG2E, a.y * LOG2E};
      A22[2 * q + 1] = (f32x2){a.z * LOG2E, a.w * LOG2E};
      Cv2[2 * q]     = (f32x2){c.x, c.y};
      Cv2[2 * q + 1] = (f32x2){c.z, c.w};
    }
#pragma unroll
    for (int m = 0; m < 8; ++m)
      h2[m] = (f32x2){(float)pk.v[2 * m], (float)pk.v[2 * m + 1]};
  }
  const float Dpv = Dp[d];

  const size_t base = ((size_t)b * L_ + l0) * D_ + d;
  const bf16* dtp = dtb + base;
  const bf16* xp = xb + base;
  float* op = out + base;

  float cdt[4], cx[4];
#pragma unroll
  for (int u = 0; u < 4; ++u) {
    cdt[u] = (float)dtp[(size_t)u * D_];
    cx[u]  = (float)xp[(size_t)u * D_];
  }

  float4 nb[4];
#pragma unroll
  for (int q = 0; q < 4; ++q) nb[q] = *(const float4*)(bxp + q * 4);

  f32x2 e2[8];
#define CALC_E(cn)                                                       \
  {                                                                      \
    const f32x2 cc2 = {(cn), (cn)};                                      \
    _Pragma("unroll")                                                    \
    for (int q = 0; q < 8; ++q) {                                        \
      f32x2 g = cc2 * A22[q];                                            \
      e2[q] = (f32x2){__builtin_amdgcn_exp2f(g.x), __builtin_amdgcn_exp2f(g.y)}; \
    }                                                                    \
  }

  CALC_E(cdt[0]);   // e2 for step 0

#define P3_STEP(i, ip1, c0, x0, cn)                                      \
  {                                                                      \
    const f32x2 c2 = {(c0), (c0)};                                       \
    f32x2 y2 = {Dpv * (x0), 0.f};                                        \
    float4 tb[4];                                                        \
    _Pragma("unroll")                                                    \
    for (int q = 0; q < 4; ++q)                                          \
      tb[q] = *(const float4*)(bxp + (ip1) * N_ + q * 4);                \
    _Pragma("unroll")                                                    \
    for (int q = 0; q < 4; ++q) {                                        \
      const f32x2 b0 = {nb[q].x, nb[q].y}, b1 = {nb[q].z, nb[q].w};      \
      h2[2 * q]     = e2[2 * q]     * h2[2 * q]     + c2 * b0;           \
      h2[2 * q + 1] = e2[2 * q + 1] * h2[2 * q + 1] + c2 * b1;           \
      y2 = y2 + h2[2 * q] * Cv2[2 * q];                                  \
      y2 = y2 + h2[2 * q + 1] * Cv2[2 * q + 1];                          \
    }                                                                    \
    CALC_E(cn);                        /* next step's exponentials */    \
    _Pragma("unroll")                                                    \
    for (int q = 0; q < 4; ++q) nb[q] = tb[q];                           \
    op[(size_t)(i) * D_] = y2.x + y2.y;                                  \
  }

  for (int i0 = 0; i0 < SLEN_ - 4; i0 += 4) {
#pragma unroll
    for (int u = 0; u < 4; ++u) {
      const int i = i0 + u;
      const float c0 = cdt[u], x0 = cx[u];
      cdt[u] = (float)dtp[(size_t)(i + 4) * D_];
      cx[u]  = (float)xp[(size_t)(i + 4) * D_];
      // next step's dt: u<3 -> original cdt[u+1] (= dt[i+1]);
      // u==3 -> cdt[0] already reloaded with dt[i0+4] at u=0.
      const float cn = cdt[(u + 1) & 3];
      P3_STEP(i, i + 1, c0, x0, cn);
    }
  }
#pragma unroll
  for (int u = 0; u < 4; ++u) {
    const int i = SLEN_ - 4 + u;
    const int ip1 = (u < 3) ? i + 1 : i;
    const float cn = (u < 3) ? cdt[u + 1] : cdt[3];   // u==3: e2 unused after
    P3_STEP(i, ip1, cdt[u], cx[u], cn);
  }
#undef P3_STEP
#undef CALC_E
}

// ---------------- launch ----------------
extern "C" void kernel_launch(void* const* d_in, const int* in_sizes, int n_in,
                              void* d_out, int out_size, void* d_ws, size_t ws_size,
                              hipStream_t stream) {
  const float* x  = (const float*)d_in[0];
  const float* A  = (const float*)d_in[1];
  const float* Wb = (const float*)d_in[2];
  const float* C  = (const float*)d_in[3];
  const float* Dp = (const float*)d_in[4];
  const float* Wd = (const float*)d_in[5];
  const float* bd = (const float*)d_in[6];
  float* out = (float*)d_out;

  char* ws = (char*)d_ws;
  bf16*  dtb  = (bf16*)ws;                                  // 32 MB [M,D] bf16
  bf16*  xb   = (bf16*)(ws + (size_t)33554432);             // 32 MB [M,K] bf16
  bf16*  wdb  = (bf16*)(ws + (size_t)67108864);             //  2 MB [D,K] bf16
  float* bx   = (float*)(ws + (size_t)69206016);            //  1 MB [M,16] f32
  bf16*  hseg = (bf16*)(ws + (size_t)70254592);             // 16 MB [B][SEG][D][N] bf16
  float* stot = (float*)(ws + (size_t)87031808);            //  2 MB [B][SEG][D] f32

  prep_x<<<dim3(2048), 256, 0, stream>>>(x, Wb, Wd, xb, wdb, bx);
  gemm_dt<<<dim3((M_ / 128) * (D_ / 128)), 256, 0, stream>>>(xb, wdb, bd, dtb);
  scan_p1<<<dim3(B_ * 4 * SEG_), 256, 0, stream>>>(dtb, bx, A, hseg, stot);
  scan_combine<<<dim3(B_ * (D_ / 16)), 256, 0, stream>>>(A, hseg, stot);
  scan_p3<<<dim3(B_ * 4 * SEG_), 256, 0, stream>>>(dtb, bx, xb, A, C, Dp, hseg, out);
}

// Round 18
// 153.624 us; speedup vs baseline: 1.1861x; 1.0135x over previous
//
#include <hip/hip_runtime.h>
#include <hip/hip_bf16.h>
#include <stdint.h>

#define B_ 8
#define L_ 2048
#define D_ 1024
#define N_ 16
#define M_ (B_ * L_)   // 16384 rows
#define K_ D_          // 1024
#define SEG_ 64
#define SLEN_ (L_ / SEG_)   // 32
#define LOG2E 1.44269504088896341f

typedef __bf16 bf16;
typedef __bf16 bf16x8 __attribute__((ext_vector_type(8)));
typedef float f32x4 __attribute__((ext_vector_type(4)));
typedef float f32x2 __attribute__((ext_vector_type(2)));

// ---------------- prep_x: blocks <1024: x->bf16 + Bx MFMA; >=1024: Wd cvt ----
__global__ __launch_bounds__(256) void prep_x(const float* __restrict__ x,
                                              const float* __restrict__ Wb,
                                              const float* __restrict__ Wd,
                                              bf16* __restrict__ xb,
                                              bf16* __restrict__ wdb,
                                              float* __restrict__ Bx) {
  const int bi = blockIdx.x;
  if (bi >= 1024) {
    const int i = (bi - 1024) * 256 + threadIdx.x;
    float4 v = ((const float4*)Wd)[i];
    union { bf16 h[4]; uint2 u; } p;
    p.h[0] = (bf16)v.x; p.h[1] = (bf16)v.y; p.h[2] = (bf16)v.z; p.h[3] = (bf16)v.w;
    ((uint2*)wdb)[i] = p.u;
    return;
  }
  const int lane = threadIdx.x & 63;
  const int wave = threadIdx.x >> 6;
  const int row0 = bi * 16;
  const int fr = lane & 15;
  const int kg = (lane >> 4) * 8;
  const int k0 = wave * 256;
  const float* gx = x + (size_t)(row0 + fr) * K_ + k0 + kg;
  const float* gw = Wb + (size_t)fr * K_ + k0 + kg;
  bf16* gxb = xb + (size_t)(row0 + fr) * K_ + k0 + kg;

  f32x4 acc = {};
#pragma unroll 8
  for (int kt = 0; kt < 8; ++kt) {
    float4 v0 = *(const float4*)(gx + kt * 32);
    float4 v1 = *(const float4*)(gx + kt * 32 + 4);
    float4 w0 = *(const float4*)(gw + kt * 32);
    float4 w1 = *(const float4*)(gw + kt * 32 + 4);
    union { bf16 h[8]; bf16x8 v; uint4 u; } p;
    p.h[0] = (bf16)v0.x; p.h[1] = (bf16)v0.y; p.h[2] = (bf16)v0.z; p.h[3] = (bf16)v0.w;
    p.h[4] = (bf16)v1.x; p.h[5] = (bf16)v1.y; p.h[6] = (bf16)v1.z; p.h[7] = (bf16)v1.w;
    *(uint4*)(gxb + kt * 32) = p.u;
    union { bf16 h[8]; bf16x8 v; } wp;
    wp.h[0] = (bf16)w0.x; wp.h[1] = (bf16)w0.y; wp.h[2] = (bf16)w0.z; wp.h[3] = (bf16)w0.w;
    wp.h[4] = (bf16)w1.x; wp.h[5] = (bf16)w1.y; wp.h[6] = (bf16)w1.z; wp.h[7] = (bf16)w1.w;
    acc = __builtin_amdgcn_mfma_f32_16x16x32_bf16(p.v, wp.v, acc, 0, 0, 0);
  }

  __shared__ float red[4][16][17];
  const int orow = (lane >> 4) * 4, ocol = fr;
#pragma unroll
  for (int r = 0; r < 4; ++r) red[wave][orow + r][ocol] = acc[r];
  __syncthreads();
  const int rr = threadIdx.x >> 4, cc = threadIdx.x & 15;
  const float s = red[0][rr][cc] + red[1][rr][cc] + red[2][rr][cc] + red[3][rr][cc];
  Bx[(size_t)(row0 + rr) * N_ + cc] = s;
}

// ---------------- async global->LDS helper (16B) ----------------
__device__ inline void gload_lds16(const bf16* g, bf16* l) {
  __builtin_amdgcn_global_load_lds(
      (const __attribute__((address_space(1))) void*)g,
      (__attribute__((address_space(3))) void*)l, 16, 0, 0);
}

__device__ inline float softplus_f(float z) {
  return fmaxf(z, 0.f) + __logf(1.f + __expf(-fabsf(z)));
}

// ---------------- dt GEMM: R8-proven 2-phase (54.5 us / 630 TF) ----------------
__global__ __launch_bounds__(256) void gemm_dt(const bf16* __restrict__ Xb,
                                               const bf16* __restrict__ Wdb,
                                               const float* __restrict__ bd,
                                               bf16* __restrict__ dtb) {
  __shared__ bf16 As[2][128 * 32];
  __shared__ bf16 Bs[2][128 * 32];
  const int tid = threadIdx.x;
  const int lane = tid & 63;
  const int wave = tid >> 6;
  const int wr = wave >> 1, wc = wave & 1;
  const int virt = (blockIdx.x & 7) * 128 + (blockIdx.x >> 3);
  const int mt = virt >> 3, nt = virt & 7;
  const int m0 = mt * 128, n0 = nt * 128;

  const bf16* ga[2];
  const bf16* gb[2];
#pragma unroll
  for (int q = 0; q < 2; ++q) {
    const int c = tid + 256 * q;
    const int row = c >> 2;
    const int col8 = ((c & 3) ^ (row & 3)) * 8;
    ga[q] = Xb + (size_t)(m0 + row) * K_ + col8;
    gb[q] = Wdb + (size_t)(n0 + row) * K_ + col8;
  }

  f32x4 acc[4][4] = {};
  const int frow = (lane & 15);
  const int khalf = (lane >> 4);

  int aoff[4], boff[4];
#pragma unroll
  for (int i = 0; i < 4; ++i) {
    const int Ra = wr * 64 + i * 16 + frow;
    const int Rb = wc * 64 + i * 16 + frow;
    aoff[i] = Ra * 32 + (khalf ^ (Ra & 3)) * 8;
    boff[i] = Rb * 32 + (khalf ^ (Rb & 3)) * 8;
  }

#define STAGE_(buf, kt)                                         \
  {                                                             \
    gload_lds16(ga[0] + (kt), &As[buf][tid * 8]);               \
    gload_lds16(ga[1] + (kt), &As[buf][(tid + 256) * 8]);       \
    gload_lds16(gb[0] + (kt), &Bs[buf][tid * 8]);               \
    gload_lds16(gb[1] + (kt), &Bs[buf][(tid + 256) * 8]);       \
  }

  STAGE_(0, 0);
  __syncthreads();

  int cur = 0;
  for (int t = 0; t < K_ / 32; ++t) {
    if (t + 1 < K_ / 32) STAGE_(cur ^ 1, (t + 1) * 32);
    bf16x8 af[4], bfr[4];
#pragma unroll
    for (int i = 0; i < 4; ++i) af[i] = *(const bf16x8*)&As[cur][aoff[i]];
#pragma unroll
    for (int i = 0; i < 4; ++i) bfr[i] = *(const bf16x8*)&Bs[cur][boff[i]];
#pragma unroll
    for (int i = 0; i < 4; ++i)
#pragma unroll
      for (int j = 0; j < 4; ++j)
        acc[i][j] = __builtin_amdgcn_mfma_f32_16x16x32_bf16(af[i], bfr[j], acc[i][j], 0, 0, 0);
    __syncthreads();
    cur ^= 1;
  }
#undef STAGE_

  const int rbase = m0 + wr * 64 + (lane >> 4) * 4;
  const int cbase = n0 + wc * 64 + (lane & 15);
#pragma unroll
  for (int j = 0; j < 4; ++j) {
    const int col = cbase + j * 16;
    const float bias = bd[col];
#pragma unroll
    for (int i = 0; i < 4; ++i) {
      const int row = rbase + i * 16;
#pragma unroll
      for (int r = 0; r < 4; ++r) {
        float z = acc[i][j][r] + bias;
        dtb[(size_t)(row + r) * D_ + col] = (bf16)softplus_f(z);
      }
    }
  }
}

// ---------------- pass 1: per-segment summaries (packed math, bx prefetch) ----
__global__ __launch_bounds__(256) void scan_p1(
    const bf16* __restrict__ dtb, const float* __restrict__ Bx,
    const float* __restrict__ A, bf16* __restrict__ hseg,
    float* __restrict__ stot) {
  const int tid = threadIdx.x;
  const int bi = blockIdx.x;
  const int seg = bi & 63;
  const int dtile = (bi >> 6) & 3;
  const int b = bi >> 8;
  const int d = dtile * 256 + tid;
  const int l0 = seg * SLEN_;

  const float* bxp = Bx + ((size_t)b * L_ + l0) * N_;   // wave-uniform

  f32x2 A22[8];
  {
    const float4* ap = (const float4*)(A + (size_t)d * N_);
#pragma unroll
    for (int q = 0; q < 4; ++q) {
      float4 a = ap[q];
      A22[2 * q]     = (f32x2){a.x * LOG2E, a.y * LOG2E};
      A22[2 * q + 1] = (f32x2){a.z * LOG2E, a.w * LOG2E};
    }
  }

  const bf16* dtp = dtb + ((size_t)b * L_ + l0) * D_ + d;
  f32x2 h2[8] = {};
  float s = 0.f;

  float cdt[4];
#pragma unroll
  for (int u = 0; u < 4; ++u) cdt[u] = (float)dtp[(size_t)u * D_];

  float4 nb[4];
#pragma unroll
  for (int q = 0; q < 4; ++q) nb[q] = *(const float4*)(bxp + q * 4);

#define P1_STEP(i, ip1, c0)                                              \
  {                                                                      \
    s += (c0);                                                           \
    const f32x2 c2 = {(c0), (c0)};                                       \
    float4 tb[4];                                                        \
    _Pragma("unroll")                                                    \
    for (int q = 0; q < 4; ++q)                                          \
      tb[q] = *(const float4*)(bxp + (ip1) * N_ + q * 4);                \
    _Pragma("unroll")                                                    \
    for (int q = 0; q < 4; ++q) {                                        \
      const f32x2 b0 = {nb[q].x, nb[q].y}, b1 = {nb[q].z, nb[q].w};      \
      f32x2 g0 = c2 * A22[2 * q];                                        \
      f32x2 g1 = c2 * A22[2 * q + 1];                                    \
      f32x2 e0 = {__builtin_amdgcn_exp2f(g0.x), __builtin_amdgcn_exp2f(g0.y)}; \
      f32x2 e1 = {__builtin_amdgcn_exp2f(g1.x), __builtin_amdgcn_exp2f(g1.y)}; \
      h2[2 * q]     = e0 * h2[2 * q]     + c2 * b0;                      \
      h2[2 * q + 1] = e1 * h2[2 * q + 1] + c2 * b1;                      \
    }                                                                    \
    _Pragma("unroll")                                                    \
    for (int q = 0; q < 4; ++q) nb[q] = tb[q];                           \
  }

  for (int i0 = 0; i0 < SLEN_ - 4; i0 += 4) {
#pragma unroll
    for (int u = 0; u < 4; ++u) {
      const int i = i0 + u;
      const float c0 = cdt[u];
      cdt[u] = (float)dtp[(size_t)(i + 4) * D_];
      P1_STEP(i, i + 1, c0);
    }
  }
#pragma unroll
  for (int u = 0; u < 4; ++u) {
    const int i = SLEN_ - 4 + u;
    const int ip1 = (u < 3) ? i + 1 : i;
    P1_STEP(i, ip1, cdt[u]);
  }
#undef P1_STEP

  bf16* hp = hseg + (((size_t)b * SEG_ + seg) * D_ + d) * N_;
  union { bf16 v[16]; uint4 u[2]; } pk;
#pragma unroll
  for (int m = 0; m < 8; ++m) {
    pk.v[2 * m] = (bf16)h2[m].x;
    pk.v[2 * m + 1] = (bf16)h2[m].y;
  }
  ((uint4*)hp)[0] = pk.u[0];
  ((uint4*)hp)[1] = pk.u[1];
  stot[((size_t)b * SEG_ + seg) * D_ + d] = s;
}

// ---------------- pass 2: exclusive-prefix combine (in-place hseg -> h0) ----
__global__ __launch_bounds__(256) void scan_combine(
    const float* __restrict__ A, bf16* __restrict__ hseg,
    const float* __restrict__ stot) {
  const int tid = threadIdx.x;
  const int bi = blockIdx.x;          // B_ * (D_/16) = 512
  const int b = bi >> 6;
  const int d = (bi & 63) * 16 + (tid >> 4);
  const int n = tid & 15;
  const float A2 = A[(size_t)d * N_ + n] * LOG2E;

  const size_t hbase = ((size_t)b * SEG_ * D_ + d) * N_ + n;
  const size_t sbase = (size_t)b * SEG_ * D_ + d;
  float g = 0.f;
  float hs = (float)hseg[hbase];
  float st = stot[sbase];
  for (int sg = 0; sg < SEG_; ++sg) {
    const int s1 = (sg + 1 < SEG_) ? sg + 1 : sg;
    const float nhs = (float)hseg[hbase + (size_t)s1 * D_ * N_];
    const float nst = stot[sbase + (size_t)s1 * D_];
    hseg[hbase + (size_t)sg * D_ * N_] = (bf16)g;
    g = fmaf(__builtin_amdgcn_exp2f(A2 * st), g, hs);
    hs = nhs; st = nst;
  }
}

// ---------------- pass 3: recurrence from h0 (packed math, bx prefetch,
//                  nontemporal out stores — out is write-only) ---------------
__global__ __launch_bounds__(256) void scan_p3(
    const bf16* __restrict__ dtb, const float* __restrict__ Bx,
    const bf16* __restrict__ xb, const float* __restrict__ A,
    const float* __restrict__ C, const float* __restrict__ Dp,
    const bf16* __restrict__ hseg, float* __restrict__ out) {
  const int tid = threadIdx.x;
  const int bi = blockIdx.x;
  const int seg = bi & 63;
  const int dtile = (bi >> 6) & 3;
  const int b = bi >> 8;
  const int d = dtile * 256 + tid;
  const int l0 = seg * SLEN_;

  const float* bxp = Bx + ((size_t)b * L_ + l0) * N_;   // wave-uniform

  f32x2 A22[8], Cv2[8], h2[8];
  {
    const float4* ap = (const float4*)(A + (size_t)d * N_);
    const float4* cp = (const float4*)(C + (size_t)d * N_);
    const bf16* hp = hseg + (((size_t)b * SEG_ + seg) * D_ + d) * N_;
    union { uint4 u[2]; bf16 v[16]; } pk;
    pk.u[0] = ((const uint4*)hp)[0];
    pk.u[1] = ((const uint4*)hp)[1];
#pragma unroll
    for (int q = 0; q < 4; ++q) {
      float4 a = ap[q], c = cp[q];
      A22[2 * q]     = (f32x2){a.x * LOG2E, a.y * LOG2E};
      A22[2 * q + 1] = (f32x2){a.z * LOG2E, a.w * LOG2E};
      Cv2[2 * q]     = (f32x2){c.x, c.y};
      Cv2[2 * q + 1] = (f32x2){c.z, c.w};
    }
#pragma unroll
    for (int m = 0; m < 8; ++m)
      h2[m] = (f32x2){(float)pk.v[2 * m], (float)pk.v[2 * m + 1]};
  }
  const float Dpv = Dp[d];

  const size_t base = ((size_t)b * L_ + l0) * D_ + d;
  const bf16* dtp = dtb + base;
  const bf16* xp = xb + base;
  float* op = out + base;

  float cdt[4], cx[4];
#pragma unroll
  for (int u = 0; u < 4; ++u) {
    cdt[u] = (float)dtp[(size_t)u * D_];
    cx[u]  = (float)xp[(size_t)u * D_];
  }
  float4 nb[4];
#pragma unroll
  for (int q = 0; q < 4; ++q) nb[q] = *(const float4*)(bxp + q * 4);

#define P3_STEP(i, ip1, c0, x0)                                          \
  {                                                                      \
    const f32x2 c2 = {(c0), (c0)};                                       \
    f32x2 y2 = {Dpv * (x0), 0.f};                                        \
    float4 tb[4];                                                        \
    _Pragma("unroll")                                                    \
    for (int q = 0; q < 4; ++q)                                          \
      tb[q] = *(const float4*)(bxp + (ip1) * N_ + q * 4);                \
    _Pragma("unroll")                                                    \
    for (int q = 0; q < 4; ++q) {                                        \
      const f32x2 b0 = {nb[q].x, nb[q].y}, b1 = {nb[q].z, nb[q].w};      \
      f32x2 g0 = c2 * A22[2 * q];                                        \
      f32x2 g1 = c2 * A22[2 * q + 1];                                    \
      f32x2 e0 = {__builtin_amdgcn_exp2f(g0.x), __builtin_amdgcn_exp2f(g0.y)}; \
      f32x2 e1 = {__builtin_amdgcn_exp2f(g1.x), __builtin_amdgcn_exp2f(g1.y)}; \
      h2[2 * q]     = e0 * h2[2 * q]     + c2 * b0;                      \
      h2[2 * q + 1] = e1 * h2[2 * q + 1] + c2 * b1;                      \
      y2 = y2 + h2[2 * q] * Cv2[2 * q];                                  \
      y2 = y2 + h2[2 * q + 1] * Cv2[2 * q + 1];                          \
    }                                                                    \
    _Pragma("unroll")                                                    \
    for (int q = 0; q < 4; ++q) nb[q] = tb[q];                           \
    __builtin_nontemporal_store(y2.x + y2.y, &op[(size_t)(i) * D_]);     \
  }

  for (int i0 = 0; i0 < SLEN_ - 4; i0 += 4) {
#pragma unroll
    for (int u = 0; u < 4; ++u) {
      const int i = i0 + u;
      const float c0 = cdt[u], x0 = cx[u];
      cdt[u] = (float)dtp[(size_t)(i + 4) * D_];
      cx[u]  = (float)xp[(size_t)(i + 4) * D_];
      P3_STEP(i, i + 1, c0, x0);
    }
  }
#pragma unroll
  for (int u = 0; u < 4; ++u) {
    const int i = SLEN_ - 4 + u;
    const int ip1 = (u < 3) ? i + 1 : i;
    P3_STEP(i, ip1, cdt[u], cx[u]);
  }
#undef P3_STEP
}

// ---------------- launch ----------------
extern "C" void kernel_launch(void* const* d_in, const int* in_sizes, int n_in,
                              void* d_out, int out_size, void* d_ws, size_t ws_size,
                              hipStream_t stream) {
  const float* x  = (const float*)d_in[0];
  const float* A  = (const float*)d_in[1];
  const float* Wb = (const float*)d_in[2];
  const float* C  = (const float*)d_in[3];
  const float* Dp = (const float*)d_in[4];
  const float* Wd = (const float*)d_in[5];
  const float* bd = (const float*)d_in[6];
  float* out = (float*)d_out;

  char* ws = (char*)d_ws;
  bf16*  dtb  = (bf16*)ws;                                  // 32 MB [M,D] bf16
  bf16*  xb   = (bf16*)(ws + (size_t)33554432);             // 32 MB [M,K] bf16
  bf16*  wdb  = (bf16*)(ws + (size_t)67108864);             //  2 MB [D,K] bf16
  float* bx   = (float*)(ws + (size_t)69206016);            //  1 MB [M,16] f32
  bf16*  hseg = (bf16*)(ws + (size_t)70254592);             // 16 MB [B][SEG][D][N] bf16
  float* stot = (float*)(ws + (size_t)87031808);            //  2 MB [B][SEG][D] f32

  prep_x<<<dim3(2048), 256, 0, stream>>>(x, Wb, Wd, xb, wdb, bx);
  gemm_dt<<<dim3((M_ / 128) * (D_ / 128)), 256, 0, stream>>>(xb, wdb, bd, dtb);
  scan_p1<<<dim3(B_ * 4 * SEG_), 256, 0, stream>>>(dtb, bx, A, hseg, stot);
  scan_combine<<<dim3(B_ * (D_ / 16)), 256, 0, stream>>>(A, hseg, stot);
  scan_p3<<<dim3(B_ * 4 * SEG_), 256, 0, stream>>>(dtb, bx, xb, A, C, Dp, hseg, out);
}